// Round 10
// baseline (946.234 us; speedup 1.0000x reference)
//
#include <hip/hip_runtime.h>
#include <hip/hip_bf16.h>
#include <math.h>

#define NROWS 1048576
#define D 256
#define C 65
#define MT 4                 // cluster tiles of 16 -> c 0..63 via MFMA; c=64 via VALU
#define KS 8                 // k-steps of 32 (K=256)
#define WAVES 8              // 512-thread blocks: one wfrag shared by 8 waves
#define TILES_PER_WAVE 4
#define TILES_PER_BLOCK 32   // 8 waves * 4 -> 512 rows/block, grid 2048

typedef float f32x4  __attribute__((ext_vector_type(4)));
typedef short bf16x8 __attribute__((ext_vector_type(8)));

__device__ __forceinline__ short f2bf(float f) {
    __hip_bfloat16 h = __float2bfloat16(f);   // RNE hw cvt
    return *reinterpret_cast<short*>(&h);
}

// --- Pre-kernel: weight norms -> d_ws (65 floats). One wave per cluster. ---
__global__ void wn_kernel(const float* __restrict__ w, float* __restrict__ wn) {
    int c = blockIdx.x;
    int l = threadIdx.x;
    float s = 0.f;
    #pragma unroll
    for (int d = l; d < D; d += 64) {
        float v = w[c * D + d];
        s = fmaf(v, v, s);
    }
    #pragma unroll
    for (int off = 32; off; off >>= 1) s += __shfl_down(s, off);
    if (l == 0) wn[c] = sqrtf(s);
}

// --- Main kernel: round-7 per-wave structure (half-tile pipelined loads,
// bf16 MFMA c<64 + VALU c=64, full 16x65-line store restage) at 8 waves/block.
// obuf shared by wave pairs (ping-pong, lgkm-only raw barriers: no vmcnt drain
// of the cross-tile prefetch). LDS 49.9KB -> 3 blocks/CU = 24 waves/CU (75%).
__global__ __launch_bounds__(512, 6) void scluster_mfma(
    const float* __restrict__ x, const float* __restrict__ w,
    const float* __restrict__ wn, float* __restrict__ out)
{
    __shared__ bf16x8 wfrag[MT * KS * 64];   // 32KB prepacked, prenormalized A-frags
    __shared__ float  wb64[D];               // 1KB: w_hat[64][*] in f32
    __shared__ float  obuf[WAVES / 2][16 * C]; // 16.6KB: per-PAIR 16x65 staging

    const int tid  = threadIdx.x;
    const int wv   = tid >> 6;
    const int l    = tid & 63;
    const int g    = l >> 4;     // k-group within fragment
    const int jrow = l & 15;     // this lane's x-row; owned end-to-end

    const int   tile0 = blockIdx.x * TILES_PER_BLOCK + wv * TILES_PER_WAVE;
    const size_t row0 = (size_t)tile0 * 16 + jrow;
    const float* __restrict__ xp0 = x + row0 * D + g * 8;

    // ---- issue tile0/half0 loads FIRST: HBM latency hides under staging+barrier
    f32x4 p[8];                  // rolling half-tile load buffer (32 VGPR)
    #pragma unroll
    for (int k = 0; k < 4; ++k) {
        p[2 * k]     = *reinterpret_cast<const f32x4*>(xp0 + k * 32);
        p[2 * k + 1] = *reinterpret_cast<const f32x4*>(xp0 + k * 32 + 4);
    }

    // ---- stage A-fragments: f=(m,ks,lane): w_hat[m*16+(lane&15)][ks*32+(lane>>4)*8+j]
    #pragma unroll 1
    for (int f = tid; f < MT * KS * 64; f += 512) {
        const int m  = f >> 9;
        const int ks = (f >> 6) & 7;
        const int ll = f & 63;
        const int c    = m * 16 + (ll & 15);
        const int koff = ks * 32 + (ll >> 4) * 8;
        const float inv = __builtin_amdgcn_rcpf(wn[c]);
        const f32x4 a = *reinterpret_cast<const f32x4*>(&w[c * D + koff]);
        const f32x4 b = *reinterpret_cast<const f32x4*>(&w[c * D + koff + 4]);
        bf16x8 fr;
        fr[0] = f2bf(a.x * inv); fr[1] = f2bf(a.y * inv);
        fr[2] = f2bf(a.z * inv); fr[3] = f2bf(a.w * inv);
        fr[4] = f2bf(b.x * inv); fr[5] = f2bf(b.y * inv);
        fr[6] = f2bf(b.z * inv); fr[7] = f2bf(b.w * inv);
        wfrag[f] = fr;
    }
    if (tid < 64) {
        const float inv = __builtin_amdgcn_rcpf(wn[64]);
        const f32x4 a = *reinterpret_cast<const f32x4*>(&w[64 * D + tid * 4]);
        f32x4 v; v.x = a.x * inv; v.y = a.y * inv; v.z = a.z * inv; v.w = a.w * inv;
        *reinterpret_cast<f32x4*>(&wb64[tid * 4]) = v;
    }
    __syncthreads();

    float* const tb = obuf[wv >> 1];

    #pragma unroll 1
    for (int it = 0; it < TILES_PER_WAVE; ++it) {
        const float* __restrict__ xp = xp0 + (size_t)it * 16 * D;        // this tile
        const float* __restrict__ xq = xp0 + (size_t)(it + 1) * 16 * D;  // next tile

        f32x4 acc[MT];
        #pragma unroll
        for (int m = 0; m < MT; ++m) acc[m] = f32x4{0.f, 0.f, 0.f, 0.f};
        float xn2 = 0.f, acc64 = 0.f;

        bf16x8 xfA[4], xfB[4];

        // ---- consume half0 (waits vmcnt), cvt + xn2 + c64 partial
        #pragma unroll
        for (int k = 0; k < 4; ++k) {
            const f32x4 a = p[2 * k], b = p[2 * k + 1];
            xn2 = fmaf(a.x, a.x, xn2); xn2 = fmaf(a.y, a.y, xn2);
            xn2 = fmaf(a.z, a.z, xn2); xn2 = fmaf(a.w, a.w, xn2);
            xn2 = fmaf(b.x, b.x, xn2); xn2 = fmaf(b.y, b.y, xn2);
            xn2 = fmaf(b.z, b.z, xn2); xn2 = fmaf(b.w, b.w, xn2);
            const f32x4 wa = *reinterpret_cast<const f32x4*>(&wb64[g * 8 + k * 32]);
            const f32x4 wb = *reinterpret_cast<const f32x4*>(&wb64[g * 8 + k * 32 + 4]);
            acc64 = fmaf(wa.x, a.x, acc64); acc64 = fmaf(wa.y, a.y, acc64);
            acc64 = fmaf(wa.z, a.z, acc64); acc64 = fmaf(wa.w, a.w, acc64);
            acc64 = fmaf(wb.x, b.x, acc64); acc64 = fmaf(wb.y, b.y, acc64);
            acc64 = fmaf(wb.z, b.z, acc64); acc64 = fmaf(wb.w, b.w, acc64);
            bf16x8 xf;
            xf[0] = f2bf(a.x); xf[1] = f2bf(a.y); xf[2] = f2bf(a.z); xf[3] = f2bf(a.w);
            xf[4] = f2bf(b.x); xf[5] = f2bf(b.y); xf[6] = f2bf(b.z); xf[7] = f2bf(b.w);
            xfA[k] = xf;
        }
        // ---- issue half1 loads NOW (hidden under MFMA phase A)
        #pragma unroll
        for (int k = 0; k < 4; ++k) {
            p[2 * k]     = *reinterpret_cast<const f32x4*>(xp + 128 + k * 32);
            p[2 * k + 1] = *reinterpret_cast<const f32x4*>(xp + 128 + k * 32 + 4);
        }
        __builtin_amdgcn_sched_barrier(0);
        // ---- MFMA phase A: ks = 0..3
        #pragma unroll
        for (int ks = 0; ks < 4; ++ks)
            #pragma unroll
            for (int m = 0; m < MT; ++m)
                acc[m] = __builtin_amdgcn_mfma_f32_16x16x32_bf16(
                    wfrag[(m * KS + ks) * 64 + l], xfA[ks], acc[m], 0, 0, 0);

        // ---- consume half1
        #pragma unroll
        for (int k = 0; k < 4; ++k) {
            const f32x4 a = p[2 * k], b = p[2 * k + 1];
            xn2 = fmaf(a.x, a.x, xn2); xn2 = fmaf(a.y, a.y, xn2);
            xn2 = fmaf(a.z, a.z, xn2); xn2 = fmaf(a.w, a.w, xn2);
            xn2 = fmaf(b.x, b.x, xn2); xn2 = fmaf(b.y, b.y, xn2);
            xn2 = fmaf(b.z, b.z, xn2); xn2 = fmaf(b.w, b.w, xn2);
            const f32x4 wa = *reinterpret_cast<const f32x4*>(&wb64[g * 8 + (k + 4) * 32]);
            const f32x4 wb = *reinterpret_cast<const f32x4*>(&wb64[g * 8 + (k + 4) * 32 + 4]);
            acc64 = fmaf(wa.x, a.x, acc64); acc64 = fmaf(wa.y, a.y, acc64);
            acc64 = fmaf(wa.z, a.z, acc64); acc64 = fmaf(wa.w, a.w, acc64);
            acc64 = fmaf(wb.x, b.x, acc64); acc64 = fmaf(wb.y, b.y, acc64);
            acc64 = fmaf(wb.z, b.z, acc64); acc64 = fmaf(wb.w, b.w, acc64);
            bf16x8 xf;
            xf[0] = f2bf(a.x); xf[1] = f2bf(a.y); xf[2] = f2bf(a.z); xf[3] = f2bf(a.w);
            xf[4] = f2bf(b.x); xf[5] = f2bf(b.y); xf[6] = f2bf(b.z); xf[7] = f2bf(b.w);
            xfB[k] = xf;
        }
        // ---- issue half0 of NEXT tile (hidden under MFMA phase B + epilogue)
        if (it < TILES_PER_WAVE - 1) {
            #pragma unroll
            for (int k = 0; k < 4; ++k) {
                p[2 * k]     = *reinterpret_cast<const f32x4*>(xq + k * 32);
                p[2 * k + 1] = *reinterpret_cast<const f32x4*>(xq + k * 32 + 4);
            }
        }
        __builtin_amdgcn_sched_barrier(0);
        // ---- MFMA phase B: ks = 4..7
        #pragma unroll
        for (int ks = 0; ks < 4; ++ks)
            #pragma unroll
            for (int m = 0; m < MT; ++m)
                acc[m] = __builtin_amdgcn_mfma_f32_16x16x32_bf16(
                    wfrag[(m * KS + ks + 4) * 64 + l], xfB[ks], acc[m], 0, 0, 0);

        // ---- epilogue: reduces, softmax
        xn2   += __shfl_xor(xn2, 16);   xn2   += __shfl_xor(xn2, 32);
        acc64 += __shfl_xor(acc64, 16); acc64 += __shfl_xor(acc64, 32);
        const float rxn = __builtin_amdgcn_rcpf(sqrtf(xn2));
        const float s64 = acc64 * rxn;

        float mx = s64;
        #pragma unroll
        for (int m = 0; m < MT; ++m) {
            #pragma unroll
            for (int r = 0; r < 4; ++r) {
                const float v = acc[m][r] * rxn;
                acc[m][r] = v;
                mx = fmaxf(mx, v);
            }
        }
        mx = fmaxf(mx, __shfl_xor(mx, 16));
        mx = fmaxf(mx, __shfl_xor(mx, 32));

        const float e64 = __expf(s64 - mx);
        float sum = (g == 0) ? e64 : 0.f;
        #pragma unroll
        for (int m = 0; m < MT; ++m) {
            #pragma unroll
            for (int r = 0; r < 4; ++r) {
                const float e = __expf(acc[m][r] - mx);
                acc[m][r] = e;
                sum += e;
            }
        }
        sum += __shfl_xor(sum, 16);
        sum += __shfl_xor(sum, 32);
        const float rs = __builtin_amdgcn_rcpf(sum);

        // ---- full-tile restage through the PAIR's buffer, ping-pong.
        // 16*65 floats = 4160B = 65 aligned full lines -> NT f32x4 stores.
        auto emit = [&]() {
            #pragma unroll
            for (int m = 0; m < MT; ++m) {
                #pragma unroll
                for (int r = 0; r < 4; ++r)
                    tb[jrow * C + m * 16 + g * 4 + r] = acc[m][r] * rs;
            }
            if (g == 0) tb[jrow * C + 64] = e64 * rs;
            asm volatile("s_waitcnt lgkmcnt(0)" ::: "memory");  // ds order (same wave)
            const size_t gb = (size_t)(tile0 + it) * 16 * C;
            #pragma unroll
            for (int rd = 0; rd < 4; ++rd) {
                const int idx = rd * 64 + l;
                const f32x4 v = *reinterpret_cast<const f32x4*>(&tb[idx * 4]);
                __builtin_nontemporal_store(v, reinterpret_cast<f32x4*>(&out[gb + idx * 4]));
            }
            if (l < 4) {
                const int idx = 256 + l;
                const f32x4 v = *reinterpret_cast<const f32x4*>(&tb[idx * 4]);
                __builtin_nontemporal_store(v, reinterpret_cast<f32x4*>(&out[gb + idx * 4]));
            }
        };
        if (!(wv & 1)) emit();
        // raw barrier w/ lgkm-only wait: do NOT drain vmcnt (prefetch stays in flight)
        asm volatile("s_waitcnt lgkmcnt(0)\n\ts_barrier" ::: "memory");
        if (wv & 1) emit();
        asm volatile("s_waitcnt lgkmcnt(0)\n\ts_barrier" ::: "memory");
    }
}

extern "C" void kernel_launch(void* const* d_in, const int* in_sizes, int n_in,
                              void* d_out, int out_size, void* d_ws, size_t ws_size,
                              hipStream_t stream) {
    const float* x = (const float*)d_in[0];
    const float* w = (const float*)d_in[1];
    float* out = (float*)d_out;
    float* wn = (float*)d_ws;

    wn_kernel<<<C, 64, 0, stream>>>(w, wn);
    scluster_mfma<<<NROWS / 16 / TILES_PER_BLOCK, 512, 0, stream>>>(x, w, wn, out);
}

// Round 11
// 649.728 us; speedup vs baseline: 1.4564x; 1.4564x over previous
//
#include <hip/hip_runtime.h>
#include <hip/hip_bf16.h>
#include <math.h>

#define NROWS 1048576
#define D 256
#define C 65
#define MT 4                 // cluster tiles of 16 -> c 0..63 via MFMA; c=64 via VALU
#define KS 8                 // k-steps of 32 (K=256)
#define WAVES 8              // 512-thread blocks, one shared wfrag, PER-WAVE obuf
#define TILES_PER_WAVE 4
#define TILES_PER_BLOCK 32   // 8 waves * 4 -> 512 rows/block, grid 2048

typedef float f32x4  __attribute__((ext_vector_type(4)));
typedef short bf16x8 __attribute__((ext_vector_type(8)));

__device__ __forceinline__ short f2bf(float f) {
    __hip_bfloat16 h = __float2bfloat16(f);   // RNE hw cvt
    return *reinterpret_cast<short*>(&h);
}

// --- Pre-kernel: weight norms -> d_ws (65 floats). One wave per cluster. ---
__global__ void wn_kernel(const float* __restrict__ w, float* __restrict__ wn) {
    int c = blockIdx.x;
    int l = threadIdx.x;
    float s = 0.f;
    #pragma unroll
    for (int d = l; d < D; d += 64) {
        float v = w[c * D + d];
        s = fmaf(v, v, s);
    }
    #pragma unroll
    for (int off = 32; off; off >>= 1) s += __shfl_down(s, off);
    if (l == 0) wn[c] = sqrtf(s);
}

// --- Main kernel: EXACT round-7 per-wave structure (half-tile pipelined loads,
// bf16 MFMA c<64 + VALU c=64, per-wave full 16x65-line store restage) at
// 8 waves/block. LDS 65.5KB -> 2 blocks/CU = 16 waves/CU (50% occ, vs 37.5%).
// launch_bounds(512,4): the SAME 128-reg budget round 7 ran clean at.
// (Round-8 lesson: fewer declared waves starves RA slack; round-10 lesson:
// more declared waves spills the ~100-reg live set. 4 is the sweet spot.)
__global__ __launch_bounds__(512, 4) void scluster_mfma(
    const float* __restrict__ x, const float* __restrict__ w,
    const float* __restrict__ wn, float* __restrict__ out)
{
    __shared__ bf16x8 wfrag[MT * KS * 64];     // 32KB prepacked, prenormalized A-frags
    __shared__ float  wb64[D];                 // 1KB: w_hat[64][*] in f32
    __shared__ float  obuf[WAVES][16 * C];     // 33.3KB: PER-WAVE 16x65 staging

    const int tid  = threadIdx.x;
    const int wv   = tid >> 6;
    const int l    = tid & 63;
    const int g    = l >> 4;     // k-group within fragment
    const int jrow = l & 15;     // this lane's x-row; owned end-to-end

    const int   tile0 = blockIdx.x * TILES_PER_BLOCK + wv * TILES_PER_WAVE;
    const size_t row0 = (size_t)tile0 * 16 + jrow;
    const float* __restrict__ xp0 = x + row0 * D + g * 8;

    // ---- issue tile0/half0 loads FIRST: HBM latency hides under staging+barrier
    f32x4 p[8];                  // rolling half-tile load buffer (32 VGPR)
    #pragma unroll
    for (int k = 0; k < 4; ++k) {
        p[2 * k]     = *reinterpret_cast<const f32x4*>(xp0 + k * 32);
        p[2 * k + 1] = *reinterpret_cast<const f32x4*>(xp0 + k * 32 + 4);
    }

    // ---- stage A-fragments: f=(m,ks,lane): w_hat[m*16+(lane&15)][ks*32+(lane>>4)*8+j]
    #pragma unroll 1
    for (int f = tid; f < MT * KS * 64; f += 512) {
        const int m  = f >> 9;
        const int ks = (f >> 6) & 7;
        const int ll = f & 63;
        const int c    = m * 16 + (ll & 15);
        const int koff = ks * 32 + (ll >> 4) * 8;
        const float inv = __builtin_amdgcn_rcpf(wn[c]);
        const f32x4 a = *reinterpret_cast<const f32x4*>(&w[c * D + koff]);
        const f32x4 b = *reinterpret_cast<const f32x4*>(&w[c * D + koff + 4]);
        bf16x8 fr;
        fr[0] = f2bf(a.x * inv); fr[1] = f2bf(a.y * inv);
        fr[2] = f2bf(a.z * inv); fr[3] = f2bf(a.w * inv);
        fr[4] = f2bf(b.x * inv); fr[5] = f2bf(b.y * inv);
        fr[6] = f2bf(b.z * inv); fr[7] = f2bf(b.w * inv);
        wfrag[f] = fr;
    }
    if (tid < 64) {
        const float inv = __builtin_amdgcn_rcpf(wn[64]);
        const f32x4 a = *reinterpret_cast<const f32x4*>(&w[64 * D + tid * 4]);
        f32x4 v; v.x = a.x * inv; v.y = a.y * inv; v.z = a.z * inv; v.w = a.w * inv;
        *reinterpret_cast<f32x4*>(&wb64[tid * 4]) = v;
    }
    __syncthreads();

    float* const tb = obuf[wv];

    #pragma unroll 1
    for (int it = 0; it < TILES_PER_WAVE; ++it) {
        const float* __restrict__ xp = xp0 + (size_t)it * 16 * D;        // this tile
        const float* __restrict__ xq = xp0 + (size_t)(it + 1) * 16 * D;  // next tile

        f32x4 acc[MT];
        #pragma unroll
        for (int m = 0; m < MT; ++m) acc[m] = f32x4{0.f, 0.f, 0.f, 0.f};
        float xn2 = 0.f, acc64 = 0.f;

        bf16x8 xfA[4], xfB[4];

        // ---- consume half0 (waits vmcnt), cvt + xn2 + c64 partial
        #pragma unroll
        for (int k = 0; k < 4; ++k) {
            const f32x4 a = p[2 * k], b = p[2 * k + 1];
            xn2 = fmaf(a.x, a.x, xn2); xn2 = fmaf(a.y, a.y, xn2);
            xn2 = fmaf(a.z, a.z, xn2); xn2 = fmaf(a.w, a.w, xn2);
            xn2 = fmaf(b.x, b.x, xn2); xn2 = fmaf(b.y, b.y, xn2);
            xn2 = fmaf(b.z, b.z, xn2); xn2 = fmaf(b.w, b.w, xn2);
            const f32x4 wa = *reinterpret_cast<const f32x4*>(&wb64[g * 8 + k * 32]);
            const f32x4 wb = *reinterpret_cast<const f32x4*>(&wb64[g * 8 + k * 32 + 4]);
            acc64 = fmaf(wa.x, a.x, acc64); acc64 = fmaf(wa.y, a.y, acc64);
            acc64 = fmaf(wa.z, a.z, acc64); acc64 = fmaf(wa.w, a.w, acc64);
            acc64 = fmaf(wb.x, b.x, acc64); acc64 = fmaf(wb.y, b.y, acc64);
            acc64 = fmaf(wb.z, b.z, acc64); acc64 = fmaf(wb.w, b.w, acc64);
            bf16x8 xf;
            xf[0] = f2bf(a.x); xf[1] = f2bf(a.y); xf[2] = f2bf(a.z); xf[3] = f2bf(a.w);
            xf[4] = f2bf(b.x); xf[5] = f2bf(b.y); xf[6] = f2bf(b.z); xf[7] = f2bf(b.w);
            xfA[k] = xf;
        }
        // ---- issue half1 loads NOW (hidden under MFMA phase A)
        #pragma unroll
        for (int k = 0; k < 4; ++k) {
            p[2 * k]     = *reinterpret_cast<const f32x4*>(xp + 128 + k * 32);
            p[2 * k + 1] = *reinterpret_cast<const f32x4*>(xp + 128 + k * 32 + 4);
        }
        __builtin_amdgcn_sched_barrier(0);
        // ---- MFMA phase A: ks = 0..3
        #pragma unroll
        for (int ks = 0; ks < 4; ++ks)
            #pragma unroll
            for (int m = 0; m < MT; ++m)
                acc[m] = __builtin_amdgcn_mfma_f32_16x16x32_bf16(
                    wfrag[(m * KS + ks) * 64 + l], xfA[ks], acc[m], 0, 0, 0);

        // ---- consume half1
        #pragma unroll
        for (int k = 0; k < 4; ++k) {
            const f32x4 a = p[2 * k], b = p[2 * k + 1];
            xn2 = fmaf(a.x, a.x, xn2); xn2 = fmaf(a.y, a.y, xn2);
            xn2 = fmaf(a.z, a.z, xn2); xn2 = fmaf(a.w, a.w, xn2);
            xn2 = fmaf(b.x, b.x, xn2); xn2 = fmaf(b.y, b.y, xn2);
            xn2 = fmaf(b.z, b.z, xn2); xn2 = fmaf(b.w, b.w, xn2);
            const f32x4 wa = *reinterpret_cast<const f32x4*>(&wb64[g * 8 + (k + 4) * 32]);
            const f32x4 wb = *reinterpret_cast<const f32x4*>(&wb64[g * 8 + (k + 4) * 32 + 4]);
            acc64 = fmaf(wa.x, a.x, acc64); acc64 = fmaf(wa.y, a.y, acc64);
            acc64 = fmaf(wa.z, a.z, acc64); acc64 = fmaf(wa.w, a.w, acc64);
            acc64 = fmaf(wb.x, b.x, acc64); acc64 = fmaf(wb.y, b.y, acc64);
            acc64 = fmaf(wb.z, b.z, acc64); acc64 = fmaf(wb.w, b.w, acc64);
            bf16x8 xf;
            xf[0] = f2bf(a.x); xf[1] = f2bf(a.y); xf[2] = f2bf(a.z); xf[3] = f2bf(a.w);
            xf[4] = f2bf(b.x); xf[5] = f2bf(b.y); xf[6] = f2bf(b.z); xf[7] = f2bf(b.w);
            xfB[k] = xf;
        }
        // ---- issue half0 of NEXT tile (hidden under MFMA phase B + epilogue)
        if (it < TILES_PER_WAVE - 1) {
            #pragma unroll
            for (int k = 0; k < 4; ++k) {
                p[2 * k]     = *reinterpret_cast<const f32x4*>(xq + k * 32);
                p[2 * k + 1] = *reinterpret_cast<const f32x4*>(xq + k * 32 + 4);
            }
        }
        __builtin_amdgcn_sched_barrier(0);
        // ---- MFMA phase B: ks = 4..7
        #pragma unroll
        for (int ks = 0; ks < 4; ++ks)
            #pragma unroll
            for (int m = 0; m < MT; ++m)
                acc[m] = __builtin_amdgcn_mfma_f32_16x16x32_bf16(
                    wfrag[(m * KS + ks + 4) * 64 + l], xfB[ks], acc[m], 0, 0, 0);

        // ---- epilogue: reduces, softmax
        xn2   += __shfl_xor(xn2, 16);   xn2   += __shfl_xor(xn2, 32);
        acc64 += __shfl_xor(acc64, 16); acc64 += __shfl_xor(acc64, 32);
        const float rxn = __builtin_amdgcn_rcpf(sqrtf(xn2));
        const float s64 = acc64 * rxn;

        float mx = s64;
        #pragma unroll
        for (int m = 0; m < MT; ++m) {
            #pragma unroll
            for (int r = 0; r < 4; ++r) {
                const float v = acc[m][r] * rxn;
                acc[m][r] = v;
                mx = fmaxf(mx, v);
            }
        }
        mx = fmaxf(mx, __shfl_xor(mx, 16));
        mx = fmaxf(mx, __shfl_xor(mx, 32));

        const float e64 = __expf(s64 - mx);
        float sum = (g == 0) ? e64 : 0.f;
        #pragma unroll
        for (int m = 0; m < MT; ++m) {
            #pragma unroll
            for (int r = 0; r < 4; ++r) {
                const float e = __expf(acc[m][r] - mx);
                acc[m][r] = e;
                sum += e;
            }
        }
        sum += __shfl_xor(sum, 16);
        sum += __shfl_xor(sum, 32);
        const float rs = __builtin_amdgcn_rcpf(sum);

        // ---- full-tile restage into PER-WAVE buffer (no cross-wave sync).
        // scatter banks (jrow+c)%32 -> <=4-way, measured 0 conflicts (r7/r9).
        #pragma unroll
        for (int m = 0; m < MT; ++m) {
            #pragma unroll
            for (int r = 0; r < 4; ++r)
                tb[jrow * C + m * 16 + g * 4 + r] = acc[m][r] * rs;
        }
        if (g == 0) tb[jrow * C + 64] = e64 * rs;
        asm volatile("s_waitcnt lgkmcnt(0)" ::: "memory");  // same-wave ds order

        // 16*65 floats = 4160B = 65 aligned full lines; coalesced NT f32x4 stores
        const size_t gb = (size_t)(tile0 + it) * 16 * C;
        #pragma unroll
        for (int rd = 0; rd < 4; ++rd) {
            const int idx = rd * 64 + l;
            const f32x4 v = *reinterpret_cast<const f32x4*>(&tb[idx * 4]);
            __builtin_nontemporal_store(v, reinterpret_cast<f32x4*>(&out[gb + idx * 4]));
        }
        if (l < 4) {
            const int idx = 256 + l;
            const f32x4 v = *reinterpret_cast<const f32x4*>(&tb[idx * 4]);
            __builtin_nontemporal_store(v, reinterpret_cast<f32x4*>(&out[gb + idx * 4]));
        }
    }
}

extern "C" void kernel_launch(void* const* d_in, const int* in_sizes, int n_in,
                              void* d_out, int out_size, void* d_ws, size_t ws_size,
                              hipStream_t stream) {
    const float* x = (const float*)d_in[0];
    const float* w = (const float*)d_in[1];
    float* out = (float*)d_out;
    float* wn = (float*)d_ws;

    wn_kernel<<<C, 64, 0, stream>>>(w, wn);
    scluster_mfma<<<NROWS / 16 / TILES_PER_BLOCK, 512, 0, stream>>>(x, w, wn, out);
}

// Round 12
// 274.571 us; speedup vs baseline: 3.4462x; 2.3663x over previous
//
#include <hip/hip_runtime.h>
#include <hip/hip_bf16.h>
#include <math.h>

#define NROWS 1048576
#define D 256
#define C 65
#define MT 4                 // cluster tiles of 16 -> c 0..63 via MFMA; c=64 via VALU
#define KS 8                 // k-steps of 32 (K=256)
#define TILES_PER_WAVE 8
#define TILES_PER_BLOCK 32   // 4 waves * 8 -> 512 rows/block, grid 2048  (round-7 config)

// d_ws layout (bytes): [0..259] wn (65 f32); [320..1343] wb64 (256 f32);
// [2048..34815] packed A-frags (2048 x bf16x8). Total needed: 34816 B.
#define WS_WB64_OFF_F 80
#define WS_FRAG_OFF_B 2048
#define WS_NEEDED 34816

typedef float f32x4  __attribute__((ext_vector_type(4)));
typedef short bf16x8 __attribute__((ext_vector_type(8)));

__device__ __forceinline__ short f2bf(float f) {
    __hip_bfloat16 h = __float2bfloat16(f);   // RNE hw cvt
    return *reinterpret_cast<short*>(&h);
}

// --- Pre-kernel 1: weight norms -> d_ws (65 floats). One wave per cluster. ---
__global__ void wn_kernel(const float* __restrict__ w, float* __restrict__ wn) {
    int c = blockIdx.x;
    int l = threadIdx.x;
    float s = 0.f;
    #pragma unroll
    for (int d = l; d < D; d += 64) {
        float v = w[c * D + d];
        s = fmaf(v, v, s);
    }
    #pragma unroll
    for (int off = 32; off; off >>= 1) s += __shfl_down(s, off);
    if (l == 0) wn[c] = sqrtf(s);
}

// --- Pre-kernel 2: prepack normalized bf16 A-frags + wb64 into d_ws.
// Blocks 0..31: frag f = b*64+lane; block 32: wb64.
__global__ void pack_kernel(const float* __restrict__ w, const float* __restrict__ wn,
                            bf16x8* __restrict__ pfrag, float* __restrict__ pwb64) {
    const int b = blockIdx.x;
    const int l = threadIdx.x;
    if (b < 32) {
        const int f  = b * 64 + l;
        const int m  = f >> 9;
        const int ks = (f >> 6) & 7;
        const int c    = m * 16 + (l & 15);
        const int koff = ks * 32 + (l >> 4) * 8;
        const float inv = __builtin_amdgcn_rcpf(wn[c]);
        const f32x4 a = *reinterpret_cast<const f32x4*>(&w[c * D + koff]);
        const f32x4 bb = *reinterpret_cast<const f32x4*>(&w[c * D + koff + 4]);
        bf16x8 fr;
        fr[0] = f2bf(a.x * inv);  fr[1] = f2bf(a.y * inv);
        fr[2] = f2bf(a.z * inv);  fr[3] = f2bf(a.w * inv);
        fr[4] = f2bf(bb.x * inv); fr[5] = f2bf(bb.y * inv);
        fr[6] = f2bf(bb.z * inv); fr[7] = f2bf(bb.w * inv);
        pfrag[f] = fr;
    } else {
        const float inv = __builtin_amdgcn_rcpf(wn[64]);
        const f32x4 a = *reinterpret_cast<const f32x4*>(&w[64 * D + l * 4]);
        f32x4 v; v.x = a.x * inv; v.y = a.y * inv; v.z = a.z * inv; v.w = a.w * inv;
        *reinterpret_cast<f32x4*>(&pwb64[l * 4]) = v;
    }
}

// --- Main kernel: EXACT round-7 structure (272us verified): 4 waves, half-tile
// pipelined x loads, bf16 MFMA c<64 + VALU c=64, per-wave full 16x65-line
// store restage, NT stores. Only change: staging copies prepacked frags from
// d_ws (33KB) instead of reading+converting w (66.5KB) when pack==1.
__global__ __launch_bounds__(256, 4) void scluster_mfma(
    const float* __restrict__ x, const float* __restrict__ w,
    const float* __restrict__ wn, const bf16x8* __restrict__ pfrag,
    const float* __restrict__ pwb64, float* __restrict__ out, const int pack)
{
    __shared__ bf16x8 wfrag[MT * KS * 64];   // 32KB prepacked, prenormalized A-frags
    __shared__ float  wb64[D];               // 1KB: w_hat[64][*] in f32
    __shared__ float  obuf[4][16 * C];       // 16.6KB per-wave 16x65 staging

    const int tid = threadIdx.x;

    if (pack) {
        // ---- stage from prepacked ws: 8 iters x 4KB coalesced, no cvt
        #pragma unroll 1
        for (int f = tid; f < MT * KS * 64; f += 256) wfrag[f] = pfrag[f];
        if (tid < 64)
            *reinterpret_cast<f32x4*>(&wb64[tid * 4]) =
                *reinterpret_cast<const f32x4*>(&pwb64[tid * 4]);
    } else {
        // ---- fallback (ws too small): round-7 in-kernel staging
        #pragma unroll 1
        for (int f = tid; f < MT * KS * 64; f += 256) {
            const int m  = f >> 9;
            const int ks = (f >> 6) & 7;
            const int ll = f & 63;
            const int c    = m * 16 + (ll & 15);
            const int koff = ks * 32 + (ll >> 4) * 8;
            const float inv = __builtin_amdgcn_rcpf(wn[c]);
            const f32x4 a = *reinterpret_cast<const f32x4*>(&w[c * D + koff]);
            const f32x4 b = *reinterpret_cast<const f32x4*>(&w[c * D + koff + 4]);
            bf16x8 fr;
            fr[0] = f2bf(a.x * inv); fr[1] = f2bf(a.y * inv);
            fr[2] = f2bf(a.z * inv); fr[3] = f2bf(a.w * inv);
            fr[4] = f2bf(b.x * inv); fr[5] = f2bf(b.y * inv);
            fr[6] = f2bf(b.z * inv); fr[7] = f2bf(b.w * inv);
            wfrag[f] = fr;
        }
        if (tid < 64) {
            const float inv = __builtin_amdgcn_rcpf(wn[64]);
            const f32x4 a = *reinterpret_cast<const f32x4*>(&w[64 * D + tid * 4]);
            f32x4 v; v.x = a.x * inv; v.y = a.y * inv; v.z = a.z * inv; v.w = a.w * inv;
            *reinterpret_cast<f32x4*>(&wb64[tid * 4]) = v;
        }
    }
    __syncthreads();

    const int wv   = tid >> 6;
    const int l    = tid & 63;
    const int g    = l >> 4;     // k-group within fragment
    const int jrow = l & 15;     // this lane's x-row; owned end-to-end

    const int   tile0 = blockIdx.x * TILES_PER_BLOCK + wv * TILES_PER_WAVE;
    const size_t row0 = (size_t)tile0 * 16 + jrow;
    const float* __restrict__ xp0 = x + row0 * D + g * 8;
    float* const tb = obuf[wv];

    f32x4 p[8];                  // rolling half-tile load buffer (32 VGPR)
    #pragma unroll
    for (int k = 0; k < 4; ++k) {
        p[2 * k]     = *reinterpret_cast<const f32x4*>(xp0 + k * 32);
        p[2 * k + 1] = *reinterpret_cast<const f32x4*>(xp0 + k * 32 + 4);
    }

    #pragma unroll 1
    for (int it = 0; it < TILES_PER_WAVE; ++it) {
        const float* __restrict__ xp = xp0 + (size_t)it * 16 * D;        // this tile
        const float* __restrict__ xq = xp0 + (size_t)(it + 1) * 16 * D;  // next tile

        f32x4 acc[MT];
        #pragma unroll
        for (int m = 0; m < MT; ++m) acc[m] = f32x4{0.f, 0.f, 0.f, 0.f};
        float xn2 = 0.f, acc64 = 0.f;

        bf16x8 xfA[4], xfB[4];

        // ---- consume half0 (waits vmcnt), cvt + xn2 + c64 partial
        #pragma unroll
        for (int k = 0; k < 4; ++k) {
            const f32x4 a = p[2 * k], b = p[2 * k + 1];
            xn2 = fmaf(a.x, a.x, xn2); xn2 = fmaf(a.y, a.y, xn2);
            xn2 = fmaf(a.z, a.z, xn2); xn2 = fmaf(a.w, a.w, xn2);
            xn2 = fmaf(b.x, b.x, xn2); xn2 = fmaf(b.y, b.y, xn2);
            xn2 = fmaf(b.z, b.z, xn2); xn2 = fmaf(b.w, b.w, xn2);
            const f32x4 wa = *reinterpret_cast<const f32x4*>(&wb64[g * 8 + k * 32]);
            const f32x4 wb = *reinterpret_cast<const f32x4*>(&wb64[g * 8 + k * 32 + 4]);
            acc64 = fmaf(wa.x, a.x, acc64); acc64 = fmaf(wa.y, a.y, acc64);
            acc64 = fmaf(wa.z, a.z, acc64); acc64 = fmaf(wa.w, a.w, acc64);
            acc64 = fmaf(wb.x, b.x, acc64); acc64 = fmaf(wb.y, b.y, acc64);
            acc64 = fmaf(wb.z, b.z, acc64); acc64 = fmaf(wb.w, b.w, acc64);
            bf16x8 xf;
            xf[0] = f2bf(a.x); xf[1] = f2bf(a.y); xf[2] = f2bf(a.z); xf[3] = f2bf(a.w);
            xf[4] = f2bf(b.x); xf[5] = f2bf(b.y); xf[6] = f2bf(b.z); xf[7] = f2bf(b.w);
            xfA[k] = xf;
        }
        // ---- issue half1 loads NOW (hidden under MFMA phase A)
        #pragma unroll
        for (int k = 0; k < 4; ++k) {
            p[2 * k]     = *reinterpret_cast<const f32x4*>(xp + 128 + k * 32);
            p[2 * k + 1] = *reinterpret_cast<const f32x4*>(xp + 128 + k * 32 + 4);
        }
        __builtin_amdgcn_sched_barrier(0);
        // ---- MFMA phase A: ks = 0..3
        #pragma unroll
        for (int ks = 0; ks < 4; ++ks)
            #pragma unroll
            for (int m = 0; m < MT; ++m)
                acc[m] = __builtin_amdgcn_mfma_f32_16x16x32_bf16(
                    wfrag[(m * KS + ks) * 64 + l], xfA[ks], acc[m], 0, 0, 0);

        // ---- consume half1
        #pragma unroll
        for (int k = 0; k < 4; ++k) {
            const f32x4 a = p[2 * k], b = p[2 * k + 1];
            xn2 = fmaf(a.x, a.x, xn2); xn2 = fmaf(a.y, a.y, xn2);
            xn2 = fmaf(a.z, a.z, xn2); xn2 = fmaf(a.w, a.w, xn2);
            xn2 = fmaf(b.x, b.x, xn2); xn2 = fmaf(b.y, b.y, xn2);
            xn2 = fmaf(b.z, b.z, xn2); xn2 = fmaf(b.w, b.w, xn2);
            const f32x4 wa = *reinterpret_cast<const f32x4*>(&wb64[g * 8 + (k + 4) * 32]);
            const f32x4 wb = *reinterpret_cast<const f32x4*>(&wb64[g * 8 + (k + 4) * 32 + 4]);
            acc64 = fmaf(wa.x, a.x, acc64); acc64 = fmaf(wa.y, a.y, acc64);
            acc64 = fmaf(wa.z, a.z, acc64); acc64 = fmaf(wa.w, a.w, acc64);
            acc64 = fmaf(wb.x, b.x, acc64); acc64 = fmaf(wb.y, b.y, acc64);
            acc64 = fmaf(wb.z, b.z, acc64); acc64 = fmaf(wb.w, b.w, acc64);
            bf16x8 xf;
            xf[0] = f2bf(a.x); xf[1] = f2bf(a.y); xf[2] = f2bf(a.z); xf[3] = f2bf(a.w);
            xf[4] = f2bf(b.x); xf[5] = f2bf(b.y); xf[6] = f2bf(b.z); xf[7] = f2bf(b.w);
            xfB[k] = xf;
        }
        // ---- issue half0 of NEXT tile (hidden under MFMA phase B + epilogue)
        if (it < TILES_PER_WAVE - 1) {
            #pragma unroll
            for (int k = 0; k < 4; ++k) {
                p[2 * k]     = *reinterpret_cast<const f32x4*>(xq + k * 32);
                p[2 * k + 1] = *reinterpret_cast<const f32x4*>(xq + k * 32 + 4);
            }
        }
        __builtin_amdgcn_sched_barrier(0);
        // ---- MFMA phase B: ks = 4..7
        #pragma unroll
        for (int ks = 0; ks < 4; ++ks)
            #pragma unroll
            for (int m = 0; m < MT; ++m)
                acc[m] = __builtin_amdgcn_mfma_f32_16x16x32_bf16(
                    wfrag[(m * KS + ks + 4) * 64 + l], xfB[ks], acc[m], 0, 0, 0);

        // ---- epilogue: reduces, softmax
        xn2   += __shfl_xor(xn2, 16);   xn2   += __shfl_xor(xn2, 32);
        acc64 += __shfl_xor(acc64, 16); acc64 += __shfl_xor(acc64, 32);
        const float rxn = __builtin_amdgcn_rcpf(sqrtf(xn2));
        const float s64 = acc64 * rxn;

        float mx = s64;
        #pragma unroll
        for (int m = 0; m < MT; ++m) {
            #pragma unroll
            for (int r = 0; r < 4; ++r) {
                const float v = acc[m][r] * rxn;
                acc[m][r] = v;
                mx = fmaxf(mx, v);
            }
        }
        mx = fmaxf(mx, __shfl_xor(mx, 16));
        mx = fmaxf(mx, __shfl_xor(mx, 32));

        const float e64 = __expf(s64 - mx);
        float sum = (g == 0) ? e64 : 0.f;
        #pragma unroll
        for (int m = 0; m < MT; ++m) {
            #pragma unroll
            for (int r = 0; r < 4; ++r) {
                const float e = __expf(acc[m][r] - mx);
                acc[m][r] = e;
                sum += e;
            }
        }
        sum += __shfl_xor(sum, 16);
        sum += __shfl_xor(sum, 32);
        const float rs = __builtin_amdgcn_rcpf(sum);

        // ---- full-tile restage into PER-WAVE buffer (round-7 verified path)
        #pragma unroll
        for (int m = 0; m < MT; ++m) {
            #pragma unroll
            for (int r = 0; r < 4; ++r)
                tb[jrow * C + m * 16 + g * 4 + r] = acc[m][r] * rs;
        }
        if (g == 0) tb[jrow * C + 64] = e64 * rs;
        asm volatile("s_waitcnt lgkmcnt(0)" ::: "memory");  // same-wave ds order

        // 16*65 floats = 4160B = 65 aligned full lines; coalesced NT f32x4 stores
        const size_t gb = (size_t)(tile0 + it) * 16 * C;
        #pragma unroll
        for (int rd = 0; rd < 4; ++rd) {
            const int idx = rd * 64 + l;
            const f32x4 v = *reinterpret_cast<const f32x4*>(&tb[idx * 4]);
            __builtin_nontemporal_store(v, reinterpret_cast<f32x4*>(&out[gb + idx * 4]));
        }
        if (l < 4) {
            const int idx = 256 + l;
            const f32x4 v = *reinterpret_cast<const f32x4*>(&tb[idx * 4]);
            __builtin_nontemporal_store(v, reinterpret_cast<f32x4*>(&out[gb + idx * 4]));
        }
    }
}

extern "C" void kernel_launch(void* const* d_in, const int* in_sizes, int n_in,
                              void* d_out, int out_size, void* d_ws, size_t ws_size,
                              hipStream_t stream) {
    const float* x = (const float*)d_in[0];
    const float* w = (const float*)d_in[1];
    float* out = (float*)d_out;
    float* wn = (float*)d_ws;
    float*  pwb64 = (float*)d_ws + WS_WB64_OFF_F;
    bf16x8* pfrag = (bf16x8*)((char*)d_ws + WS_FRAG_OFF_B);
    const int pack = (ws_size >= (size_t)WS_NEEDED) ? 1 : 0;  // ws_size fixed -> deterministic

    wn_kernel<<<C, 64, 0, stream>>>(w, wn);
    if (pack) pack_kernel<<<33, 64, 0, stream>>>(w, wn, pfrag, pwb64);
    scluster_mfma<<<NROWS / 16 / TILES_PER_BLOCK, 256, 0, stream>>>(
        x, w, wn, pfrag, pwb64, out, pack);
}